// Round 11
// baseline (211.610 us; speedup 1.0000x reference)
//
#include <hip/hip_runtime.h>
#include <math.h>

typedef __bf16 bf16x8 __attribute__((ext_vector_type(8)));
typedef __bf16 bf16x4 __attribute__((ext_vector_type(4)));
typedef float  f32x4  __attribute__((ext_vector_type(4)));

// ---------------------------------------------------------------------------
// cvt: fp32 -> bf16 for the 4 weight matrices (512x512 each)
// ---------------------------------------------------------------------------
__global__ __launch_bounds__(256)
void cvt_w(const float* __restrict__ w0, const float* __restrict__ w1,
           const float* __restrict__ w2, const float* __restrict__ w3,
           __bf16* __restrict__ d0, __bf16* __restrict__ d1,
           __bf16* __restrict__ d2, __bf16* __restrict__ d3)
{
    const int y = blockIdx.y;
    const float* s = (y == 0) ? w0 : (y == 1) ? w1 : (y == 2) ? w2 : w3;
    __bf16*      d = (y == 0) ? d0 : (y == 1) ? d1 : (y == 2) ? d2 : d3;
    const int i = blockIdx.x * 256 + threadIdx.x;
    float4 a = *(const float4*)(s + (size_t)i * 8);
    float4 b = *(const float4*)(s + (size_t)i * 8 + 4);
    bf16x8 v;
    v[0] = (__bf16)a.x; v[1] = (__bf16)a.y; v[2] = (__bf16)a.z; v[3] = (__bf16)a.w;
    v[4] = (__bf16)b.x; v[5] = (__bf16)b.y; v[6] = (__bf16)b.z; v[7] = (__bf16)b.w;
    *(bf16x8*)(d + (size_t)i * 8) = v;
}

// ---------------------------------------------------------------------------
// Fused QKV projection, z-merged (R8-proven). Tile 64x128, grid (64,4).
// ---------------------------------------------------------------------------
__global__ __launch_bounds__(256, 2)
void qkv_proj(const float* __restrict__ X,
              const __bf16* __restrict__ Wqb, const __bf16* __restrict__ Wkb,
              const __bf16* __restrict__ Wvb,
              const float* __restrict__ bq, const float* __restrict__ bk,
              const float* __restrict__ bv,
              __bf16* __restrict__ qTb, __bf16* __restrict__ kTb,
              __bf16* __restrict__ vTb)
{
    const int tid  = threadIdx.x;
    const int w    = tid >> 6;
    const int lane = tid & 63;
    const int lq   = lane & 15;
    const int quad = lane >> 4;
    const int n0    = blockIdx.x * 64 + (w >> 1) * 32;
    const int obase = blockIdx.y * 128 + (w & 1) * 64;

    const __bf16* const Wz[3] = { Wqb, Wkb, Wvb };

    f32x4 acc[3][2][4] = {};
    for (int k0 = 0; k0 < 512; k0 += 32) {
        bf16x8 af[2];
#pragma unroll
        for (int m = 0; m < 2; m++) {
            const float* xp = X + (size_t)(n0 + m * 16 + lq) * 512 + k0 + quad * 8;
            float4 x0 = *(const float4*)xp;
            float4 x1 = *(const float4*)(xp + 4);
            bf16x8 v;
            v[0] = (__bf16)x0.x; v[1] = (__bf16)x0.y; v[2] = (__bf16)x0.z; v[3] = (__bf16)x0.w;
            v[4] = (__bf16)x1.x; v[5] = (__bf16)x1.y; v[6] = (__bf16)x1.z; v[7] = (__bf16)x1.w;
            af[m] = v;
        }
#pragma unroll
        for (int z = 0; z < 3; z++) {
            bf16x8 bfr[4];
#pragma unroll
            for (int nn = 0; nn < 4; nn++)
                bfr[nn] = *(const bf16x8*)(Wz[z] + (size_t)(obase + nn * 16 + lq) * 512 + k0 + quad * 8);
#pragma unroll
            for (int m = 0; m < 2; m++)
#pragma unroll
                for (int nn = 0; nn < 4; nn++)
                    acc[z][m][nn] = __builtin_amdgcn_mfma_f32_16x16x32_bf16(af[m], bfr[nn], acc[z][m][nn], 0, 0, 0);
        }
    }

    const float* const ba[3] = { bq, bk, bv };
    const float scaling = 0.17677669529663687f;
#pragma unroll
    for (int z = 0; z < 3; z++)
#pragma unroll
        for (int m = 0; m < 2; m++)
#pragma unroll
            for (int nn = 0; nn < 4; nn++)
#pragma unroll
                for (int r = 0; r < 4; r++) {
                    const int n = n0 + m * 16 + quad * 4 + r;
                    const int o = obase + nn * 16 + lq;
                    float val = acc[z][m][nn][r] + ba[z][o];
                    const int t = n >> 2, b = n & 3;
                    const int h = o >> 5, d = o & 31;
                    const int bh = b * 16 + h;
                    if (z == 0)
                        qTb[(((size_t)bh * 1024 + t) << 5) + d] = (__bf16)(val * scaling);
                    else if (z == 1)
                        kTb[(((size_t)bh * 1024 + t) << 5) + d] = (__bf16)val;
                    else
                        vTb[(((size_t)bh * 32 + d) << 10) + t] = (__bf16)val;
                }
}

// ---------------------------------------------------------------------------
// Out projection: A bf16 [4096][512], W bf16, out fp32 + bias. Tile 64x128.
// ---------------------------------------------------------------------------
__global__ __launch_bounds__(256)
void out_proj(const __bf16* __restrict__ A, const __bf16* __restrict__ Wb,
              const float* __restrict__ bias, float* __restrict__ out)
{
    const int tid  = threadIdx.x;
    const int w    = tid >> 6;
    const int lane = tid & 63;
    const int lq   = lane & 15;
    const int quad = lane >> 4;
    const int n0    = blockIdx.x * 64 + (w >> 1) * 32;
    const int obase = blockIdx.y * 128 + (w & 1) * 64;

    f32x4 acc[2][4] = {};
    for (int k0 = 0; k0 < 512; k0 += 32) {
        bf16x8 af[2], bfr[4];
#pragma unroll
        for (int m = 0; m < 2; m++)
            af[m] = *(const bf16x8*)(A + (size_t)(n0 + m * 16 + lq) * 512 + k0 + quad * 8);
#pragma unroll
        for (int nn = 0; nn < 4; nn++)
            bfr[nn] = *(const bf16x8*)(Wb + (size_t)(obase + nn * 16 + lq) * 512 + k0 + quad * 8);
#pragma unroll
        for (int m = 0; m < 2; m++)
#pragma unroll
            for (int nn = 0; nn < 4; nn++)
                acc[m][nn] = __builtin_amdgcn_mfma_f32_16x16x32_bf16(af[m], bfr[nn], acc[m][nn], 0, 0, 0);
    }
#pragma unroll
    for (int m = 0; m < 2; m++)
#pragma unroll
        for (int nn = 0; nn < 4; nn++)
#pragma unroll
            for (int r = 0; r < 4; r++) {
                const int n = n0 + m * 16 + quad * 4 + r;
                const int o = obase + nn * 16 + lq;
                out[(size_t)n * 512 + o] = acc[m][nn][r] + bias[o];
            }
}

// ---------------------------------------------------------------------------
// MFMA attention, 16 heads per block, grid (64,4) = 256 blocks = 1/CU.
//
// DEPTH-2 BIAS PREFETCH (the point of this round): per wave, QK(h) used to
// wait on a cj batch issued only one body earlier; with ~17 MB of chip-wide
// outstanding bias, effective RTT ~= the available slack -> residual stall
// every head. Here cj(h+2) is issued at body h (slack = 2 periods) and K is
// double-buffered at depth-1, with a FIFO-audited VMEM order so NO wait ever
// drains a younger prefetch:
//   body h: [V(h)] [QK consumes kbC(h-1-issued), cjC(h-2-issued), qa]
//           [qa(h+1)] [kbN <- K(h+1)] [cjC <- bias(h+2)]  | exp/P/PV |
//           lgkm-only barrier | reduce | avg fold
// Waits: QK waits kb/qa (older than this body's prefetches); PV waits V
// (issued before the prefetches); attnb store is youngest and never waited.
// Register environment per R7: waves_per_eu(2,2) + LDS>80KB -> 256-VGPR
// budget (live set ~250: kbA/B 64 + cjA/B 64 + V 32 + acc 32 + avg 32).
// ---------------------------------------------------------------------------
__global__ __attribute__((amdgpu_waves_per_eu(2, 2))) __launch_bounds__(512)
void attn_mfma(const __bf16* __restrict__ qTb, const __bf16* __restrict__ kTb,
               const __bf16* __restrict__ vTb, const float* __restrict__ bias,
               const int* __restrict__ mask, __bf16* __restrict__ attnb,
               float* __restrict__ avgf)
{
    // [0,8448): Op[2][8][528]  [8448,8704): red[2][8][16]
    // [8704,17408): P bf16 [8][16*136].  Padded to 83.2 KB so the backend
    // targets 1 block/CU -> 256-VGPR allocation (R7-proven).
    __shared__ float smem[20800];
    float* const Op0  = smem;
    float* const red0 = &smem[8448];
    __bf16* const Pbase = (__bf16*)&smem[8704];

    const int tid  = threadIdx.x;
    const int w    = tid >> 6;
    const int lane = tid & 63;
    const int lq   = lane & 15;
    const int quad = lane >> 4;

    // bijective XCD swizzle: 256 blocks -> 32-block contiguous chunk per XCD
    const int bid = blockIdx.y * 64 + blockIdx.x;
    const int nb  = (bid & 7) * 32 + (bid >> 3);
    const int t0  = (nb & 63) * 16;
    const int b   = nb >> 6;
    const int sbase = w * 128;

    __bf16* const Pw = Pbase + w * 2176;   // 16*136 bf16 per wave

    // pack 32 mask bits (s = sbase + j*16 + quad*4 + r)
    unsigned mbits = 0;
    {
        const int* mp = mask + b * 1024 + sbase + quad * 4;
#pragma unroll
        for (int j = 0; j < 8; j++) {
            int4 m4 = *(const int4*)(mp + j * 16);
            mbits |= (unsigned)(m4.x != 0) << (j * 4 + 0);
            mbits |= (unsigned)(m4.y != 0) << (j * 4 + 1);
            mbits |= (unsigned)(m4.z != 0) << (j * 4 + 2);
            mbits |= (unsigned)(m4.w != 0) << (j * 4 + 3);
        }
    }

    // per-lane bases
    const float* const bb = bias + (((size_t)(b * 16)) << 20) +
                            (((size_t)(t0 + lq)) << 10) + sbase + quad * 4;
    const __bf16* const qp0 = qTb + (((size_t)(b * 16) * 1024 + t0) << 5) +
                              lq * 32 + quad * 8;
    const __bf16* const kp0 = kTb + ((size_t)(b * 16) << 15);
    const __bf16* const vp0 = vTb + ((size_t)(b * 16) << 15);

    // prologue (FIFO: qa, kbA(0), cjA(0), then cjB(1) youngest -> QK(0)'s
    // wait on cjA drains qa/kbA and leaves cjB in flight)
    bf16x8 qa = *(const bf16x8*)qp0;
    bf16x8 kbA[8], kbB[8];
#pragma unroll
    for (int j = 0; j < 8; j++)
        kbA[j] = *(const bf16x8*)(kp0 + (size_t)(sbase + j * 16 + lq) * 32 + quad * 8);
    f32x4 cjA[8], cjB[8];
#pragma unroll
    for (int j = 0; j < 8; j++) cjA[j] = *(const f32x4*)(bb + j * 16);
#pragma unroll
    for (int j = 0; j < 8; j++) cjB[j] = *(const f32x4*)(bb + (1ull << 20) + j * 16);

    float avg_reg[32] = {};

    // body: consumes kbC/cjC (+qa); refills kbN <- K(h+1), cjC <- bias(h+2)
    auto body = [&](bf16x8 (&kbC)[8], bf16x8 (&kbN)[8], f32x4 (&cjC)[8], int hh) {
        float* const Op  = Op0  + (hh & 1) * 4224;
        float* const red = red0 + (hh & 1) * 128;
        const __bf16* vp = vp0 + ((size_t)hh << 15);

        // V for this head: issued BEFORE this body's prefetches (older), so
        // PV's V-wait never drains them.
        bf16x8 v0r[4], v1r[4];
#pragma unroll
        for (int ks = 0; ks < 4; ks++) {
            v0r[ks] = *(const bf16x8*)(vp + (size_t)lq * 1024 + sbase + ks * 32 + quad * 8);
            v1r[ks] = *(const bf16x8*)(vp + (size_t)(16 + lq) * 1024 + sbase + ks * 32 + quad * 8);
        }
        __builtin_amdgcn_sched_barrier(0);

        // QK: kbC/qa issued 1 body ago, cjC issued 2 bodies ago -> complete
        // or nearly so; the wait leaves this body's V and the other cj buffer
        // (younger) in flight.
        f32x4 acc[8];
#pragma unroll
        for (int j = 0; j < 8; j++)
            acc[j] = __builtin_amdgcn_mfma_f32_16x16x32_bf16(kbC[j], qa, cjC[j], 0, 0, 0);
        __builtin_amdgcn_sched_barrier(0);

        // prefetch: qa(h+1), K(h+1) into kbN, bias(h+2) into the just-freed
        // cjC. Issue order (qa -> kb -> cj) keeps cj youngest. Wrap benign.
        {
            const int h1 = (hh + 1) & 15;
            const int h2 = (hh + 2) & 15;
            qa = *(const bf16x8*)(qp0 + ((size_t)h1 << 15));
            const __bf16* kpn = kp0 + ((size_t)h1 << 15);
#pragma unroll
            for (int j = 0; j < 8; j++)
                kbN[j] = *(const bf16x8*)(kpn + (size_t)(sbase + j * 16 + lq) * 32 + quad * 8);
            const float* bn = bb + ((size_t)h2 << 20);
#pragma unroll
            for (int j = 0; j < 8; j++) cjC[j] = *(const f32x4*)(bn + j * 16);
        }
        __builtin_amdgcn_sched_barrier(0);

        // exp (no max pass; scores bounded) + mask + row partial sum
        float sm = 0.f;
#pragma unroll
        for (int j = 0; j < 8; j++)
#pragma unroll
            for (int r = 0; r < 4; r++) {
                float p = __expf(acc[j][r]);
                p = ((mbits >> (j * 4 + r)) & 1u) ? 0.f : p;
                acc[j][r] = p;
                sm += p;
            }
        sm += __shfl_xor(sm, 16);
        sm += __shfl_xor(sm, 32);

        // unnormalized bf16 P into per-wave LDS region (same-wave use only)
#pragma unroll
        for (int j = 0; j < 8; j++) {
            bf16x4 pv;
            pv[0] = (__bf16)acc[j][0]; pv[1] = (__bf16)acc[j][1];
            pv[2] = (__bf16)acc[j][2]; pv[3] = (__bf16)acc[j][3];
            *(bf16x4*)&Pw[lq * 136 + j * 16 + quad * 4] = pv;
        }
        if (lane < 16) red[w * 16 + lane] = sm;

        // PV: P from LDS (lgkmcnt only), V from registers
        f32x4 o0 = {0.f, 0.f, 0.f, 0.f}, o1 = {0.f, 0.f, 0.f, 0.f};
#pragma unroll
        for (int ks = 0; ks < 4; ks++) {
            bf16x8 pa = *(const bf16x8*)&Pw[lq * 136 + ks * 32 + quad * 8];
            o0 = __builtin_amdgcn_mfma_f32_16x16x32_bf16(pa, v0r[ks], o0, 0, 0, 0);
            o1 = __builtin_amdgcn_mfma_f32_16x16x32_bf16(pa, v1r[ks], o1, 0, 0, 0);
        }
#pragma unroll
        for (int r = 0; r < 4; r++) {
            Op[w * 528 + (quad * 4 + r) * 33 + lq]      = o0[r];
            Op[w * 528 + (quad * 4 + r) * 33 + 16 + lq] = o1[r];
        }

        // raw barrier: drain LDS only; all prefetches (VMEM) stay in flight.
        __builtin_amdgcn_sched_barrier(0);
        asm volatile("s_waitcnt lgkmcnt(0)" ::: "memory");
        __builtin_amdgcn_s_barrier();
        __builtin_amdgcn_sched_barrier(0);

        // cross-wave reduce: normalized O write
        {
            const int t = tid >> 5, d = tid & 31;
            float s = 0.f, o = 0.f;
#pragma unroll
            for (int w2 = 0; w2 < 8; w2++) s += red[w2 * 16 + t];
#pragma unroll
            for (int w2 = 0; w2 < 8; w2++) o += Op[w2 * 528 + t * 33 + d];
            attnb[((size_t)(t0 + t) * 4 + b) * 512 + hh * 32 + d] = (__bf16)(o / s);
        }

        // inv for this lane's rows (t = lq) + avg fold; acc dies here
        float s_all = 0.f;
#pragma unroll
        for (int w2 = 0; w2 < 8; w2++) s_all += red[w2 * 16 + lq];
        const float inv = 1.0f / s_all;
#pragma unroll
        for (int j = 0; j < 8; j++)
#pragma unroll
            for (int r = 0; r < 4; r++)
                avg_reg[j * 4 + r] += acc[j][r] * inv;
    };

    for (int hp = 0; hp < 8; hp++) {
        body(kbA, kbB, cjA, hp * 2);
        body(kbB, kbA, cjB, hp * 2 + 1);
    }

    // head-mean store: single fp32 write (all 16 heads accumulated here)
    float* ap = avgf + ((size_t)(b * 1024 + t0 + lq) << 10) + sbase + quad * 4;
#pragma unroll
    for (int j = 0; j < 8; j++) {
        f32x4 v = { avg_reg[j * 4 + 0] * 0.0625f, avg_reg[j * 4 + 1] * 0.0625f,
                    avg_reg[j * 4 + 2] * 0.0625f, avg_reg[j * 4 + 3] * 0.0625f };
        *(f32x4*)(ap + j * 16) = v;
    }
}

// ---------------------------------------------------------------------------
extern "C" void kernel_launch(void* const* d_in, const int* in_sizes, int n_in,
                              void* d_out, int out_size, void* d_ws, size_t ws_size,
                              hipStream_t stream)
{
    const float* query     = (const float*)d_in[0];
    const float* attn_bias = (const float*)d_in[1];
    const int*   mask      = (const int*)d_in[2];
    const float* q_w       = (const float*)d_in[3];
    const float* q_b       = (const float*)d_in[4];
    const float* k_w       = (const float*)d_in[5];
    const float* k_b       = (const float*)d_in[6];
    const float* v_w       = (const float*)d_in[7];
    const float* v_b       = (const float*)d_in[8];
    const float* out_w     = (const float*)d_in[9];
    const float* out_b     = (const float*)d_in[10];

    float* out     = (float*)d_out;                 // [1024,4,512]
    float* avg_out = out + (size_t)2097152;         // [4,1024,1024]

    char* wsb = (char*)d_ws;
    __bf16* Wqb   = (__bf16*)(wsb);                         // 512 KB
    __bf16* Wkb   = (__bf16*)(wsb + ((size_t)512 << 10));
    __bf16* Wvb   = (__bf16*)(wsb + ((size_t)1 << 20));
    __bf16* Wob   = (__bf16*)(wsb + ((size_t)1 << 20) + ((size_t)512 << 10));
    __bf16* qTb   = (__bf16*)(wsb + ((size_t)2  << 20));    // 4 MB [64][1024][32]
    __bf16* kTb   = (__bf16*)(wsb + ((size_t)6  << 20));    // 4 MB [64][1024][32]
    __bf16* vTb   = (__bf16*)(wsb + ((size_t)10 << 20));    // 4 MB [64][32][1024]
    __bf16* attnb = (__bf16*)(wsb + ((size_t)14 << 20));    // 4 MB [4096][512]

    cvt_w<<<dim3(128, 4), dim3(256), 0, stream>>>(
        q_w, k_w, v_w, out_w, Wqb, Wkb, Wvb, Wob);

    qkv_proj<<<dim3(64, 4), dim3(256), 0, stream>>>(
        query, Wqb, Wkb, Wvb, q_b, k_b, v_b, qTb, kTb, vTb);

    attn_mfma<<<dim3(64, 4), dim3(512), 0, stream>>>(
        qTb, kTb, vTb, attn_bias, mask, attnb, avg_out);

    out_proj<<<dim3(64, 4), dim3(256), 0, stream>>>(attnb, Wob, out_b, out);
}

// Round 12
// 171.010 us; speedup vs baseline: 1.2374x; 1.2374x over previous
//
#include <hip/hip_runtime.h>
#include <math.h>

typedef __bf16 bf16x8 __attribute__((ext_vector_type(8)));
typedef __bf16 bf16x4 __attribute__((ext_vector_type(4)));
typedef float  f32x4  __attribute__((ext_vector_type(4)));

// ---------------------------------------------------------------------------
// cvt: fp32 -> bf16 for the 4 weight matrices (512x512 each)
// ---------------------------------------------------------------------------
__global__ __launch_bounds__(256)
void cvt_w(const float* __restrict__ w0, const float* __restrict__ w1,
           const float* __restrict__ w2, const float* __restrict__ w3,
           __bf16* __restrict__ d0, __bf16* __restrict__ d1,
           __bf16* __restrict__ d2, __bf16* __restrict__ d3)
{
    const int y = blockIdx.y;
    const float* s = (y == 0) ? w0 : (y == 1) ? w1 : (y == 2) ? w2 : w3;
    __bf16*      d = (y == 0) ? d0 : (y == 1) ? d1 : (y == 2) ? d2 : d3;
    const int i = blockIdx.x * 256 + threadIdx.x;
    float4 a = *(const float4*)(s + (size_t)i * 8);
    float4 b = *(const float4*)(s + (size_t)i * 8 + 4);
    bf16x8 v;
    v[0] = (__bf16)a.x; v[1] = (__bf16)a.y; v[2] = (__bf16)a.z; v[3] = (__bf16)a.w;
    v[4] = (__bf16)b.x; v[5] = (__bf16)b.y; v[6] = (__bf16)b.z; v[7] = (__bf16)b.w;
    *(bf16x8*)(d + (size_t)i * 8) = v;
}

// ---------------------------------------------------------------------------
// Fused QKV projection, z-merged (R8-proven). Tile 64x128, grid (64,4).
// ---------------------------------------------------------------------------
__global__ __launch_bounds__(256, 2)
void qkv_proj(const float* __restrict__ X,
              const __bf16* __restrict__ Wqb, const __bf16* __restrict__ Wkb,
              const __bf16* __restrict__ Wvb,
              const float* __restrict__ bq, const float* __restrict__ bk,
              const float* __restrict__ bv,
              __bf16* __restrict__ qTb, __bf16* __restrict__ kTb,
              __bf16* __restrict__ vTb)
{
    const int tid  = threadIdx.x;
    const int w    = tid >> 6;
    const int lane = tid & 63;
    const int lq   = lane & 15;
    const int quad = lane >> 4;
    const int n0    = blockIdx.x * 64 + (w >> 1) * 32;
    const int obase = blockIdx.y * 128 + (w & 1) * 64;

    const __bf16* const Wz[3] = { Wqb, Wkb, Wvb };

    f32x4 acc[3][2][4] = {};
    for (int k0 = 0; k0 < 512; k0 += 32) {
        bf16x8 af[2];
#pragma unroll
        for (int m = 0; m < 2; m++) {
            const float* xp = X + (size_t)(n0 + m * 16 + lq) * 512 + k0 + quad * 8;
            float4 x0 = *(const float4*)xp;
            float4 x1 = *(const float4*)(xp + 4);
            bf16x8 v;
            v[0] = (__bf16)x0.x; v[1] = (__bf16)x0.y; v[2] = (__bf16)x0.z; v[3] = (__bf16)x0.w;
            v[4] = (__bf16)x1.x; v[5] = (__bf16)x1.y; v[6] = (__bf16)x1.z; v[7] = (__bf16)x1.w;
            af[m] = v;
        }
#pragma unroll
        for (int z = 0; z < 3; z++) {
            bf16x8 bfr[4];
#pragma unroll
            for (int nn = 0; nn < 4; nn++)
                bfr[nn] = *(const bf16x8*)(Wz[z] + (size_t)(obase + nn * 16 + lq) * 512 + k0 + quad * 8);
#pragma unroll
            for (int m = 0; m < 2; m++)
#pragma unroll
                for (int nn = 0; nn < 4; nn++)
                    acc[z][m][nn] = __builtin_amdgcn_mfma_f32_16x16x32_bf16(af[m], bfr[nn], acc[z][m][nn], 0, 0, 0);
        }
    }

    const float* const ba[3] = { bq, bk, bv };
    const float scaling = 0.17677669529663687f;
#pragma unroll
    for (int z = 0; z < 3; z++)
#pragma unroll
        for (int m = 0; m < 2; m++)
#pragma unroll
            for (int nn = 0; nn < 4; nn++)
#pragma unroll
                for (int r = 0; r < 4; r++) {
                    const int n = n0 + m * 16 + quad * 4 + r;
                    const int o = obase + nn * 16 + lq;
                    float val = acc[z][m][nn][r] + ba[z][o];
                    const int t = n >> 2, b = n & 3;
                    const int h = o >> 5, d = o & 31;
                    const int bh = b * 16 + h;
                    if (z == 0)
                        qTb[(((size_t)bh * 1024 + t) << 5) + d] = (__bf16)(val * scaling);
                    else if (z == 1)
                        kTb[(((size_t)bh * 1024 + t) << 5) + d] = (__bf16)val;
                    else
                        vTb[(((size_t)bh * 32 + d) << 10) + t] = (__bf16)val;
                }
}

// ---------------------------------------------------------------------------
// Out projection: A bf16 [4096][512], W bf16, out fp32 + bias. Tile 64x128.
// ---------------------------------------------------------------------------
__global__ __launch_bounds__(256)
void out_proj(const __bf16* __restrict__ A, const __bf16* __restrict__ Wb,
              const float* __restrict__ bias, float* __restrict__ out)
{
    const int tid  = threadIdx.x;
    const int w    = tid >> 6;
    const int lane = tid & 63;
    const int lq   = lane & 15;
    const int quad = lane >> 4;
    const int n0    = blockIdx.x * 64 + (w >> 1) * 32;
    const int obase = blockIdx.y * 128 + (w & 1) * 64;

    f32x4 acc[2][4] = {};
    for (int k0 = 0; k0 < 512; k0 += 32) {
        bf16x8 af[2], bfr[4];
#pragma unroll
        for (int m = 0; m < 2; m++)
            af[m] = *(const bf16x8*)(A + (size_t)(n0 + m * 16 + lq) * 512 + k0 + quad * 8);
#pragma unroll
        for (int nn = 0; nn < 4; nn++)
            bfr[nn] = *(const bf16x8*)(Wb + (size_t)(obase + nn * 16 + lq) * 512 + k0 + quad * 8);
#pragma unroll
        for (int m = 0; m < 2; m++)
#pragma unroll
            for (int nn = 0; nn < 4; nn++)
                acc[m][nn] = __builtin_amdgcn_mfma_f32_16x16x32_bf16(af[m], bfr[nn], acc[m][nn], 0, 0, 0);
    }
#pragma unroll
    for (int m = 0; m < 2; m++)
#pragma unroll
        for (int nn = 0; nn < 4; nn++)
#pragma unroll
            for (int r = 0; r < 4; r++) {
                const int n = n0 + m * 16 + quad * 4 + r;
                const int o = obase + nn * 16 + lq;
                out[(size_t)n * 512 + o] = acc[m][nn][r] + bias[o];
            }
}

// ---------------------------------------------------------------------------
// MFMA attention, 16 heads per block, grid (64,4) = 256 blocks = 1/CU.
//
// THE POINT OF THIS ROUND: actually get 256 VGPRs. R11's counters showed
// VGPR_Count=128 despite amdgpu_waves_per_eu(2,2) -- the attribute is
// ignored, and launch_bounds' 2nd arg behaves as min-BLOCKS-per-CU on this
// toolchain ((512,2) -> 16 waves/CU -> 4/EU -> 128 VGPR cap). Every attn
// variant this session ran register-starved at 128 with live sets of
// 150-280 -> per-head spill/remat serialization, which explains the
// schedule/cache/occupancy nulls (R3/R4/R5) and the spill cliffs (R6/R11).
// __launch_bounds__(512, 1): 1 block/CU -> 2 waves/EU -> 256-VGPR budget.
//
// Pipeline = R7/R11 FIFO-clean, depth-1 (live set ~215 < 256, no spill):
//   body h: [V(h) issued] [QK consumes K(h)/qa(h)/cj(h), all issued in
//   body h-1 -> its wait leaves V(h) in flight and drains nothing newer]
//   [prefetch qa(h+1), K(h+1)->kbN, bias(h+1)->cj : youngest VMEM]
//   [exp/P/PV on V-regs] [lgkm-only barrier] [reduce] [avg fold]
// No wait ever drains a younger prefetch; bias(h+1) stays in flight from
// mid-body h to QK(h+1).
// ---------------------------------------------------------------------------
__global__ __launch_bounds__(512, 1)
void attn_mfma(const __bf16* __restrict__ qTb, const __bf16* __restrict__ kTb,
               const __bf16* __restrict__ vTb, const float* __restrict__ bias,
               const int* __restrict__ mask, __bf16* __restrict__ attnb,
               float* __restrict__ avgf)
{
    // [0,8448): Op[2][8][528]  [8448,8704): red[2][8][16]
    // [8704,17408): P bf16 [8][16*136]
    __shared__ float smem[17408];
    float* const Op0  = smem;
    float* const red0 = &smem[8448];
    __bf16* const Pbase = (__bf16*)&smem[8704];

    const int tid  = threadIdx.x;
    const int w    = tid >> 6;
    const int lane = tid & 63;
    const int lq   = lane & 15;
    const int quad = lane >> 4;

    // bijective XCD swizzle: 256 blocks -> 32-block contiguous chunk per XCD
    const int bid = blockIdx.y * 64 + blockIdx.x;
    const int nb  = (bid & 7) * 32 + (bid >> 3);
    const int t0  = (nb & 63) * 16;
    const int b   = nb >> 6;
    const int sbase = w * 128;

    __bf16* const Pw = Pbase + w * 2176;   // 16*136 bf16 per wave

    // pack 32 mask bits (s = sbase + j*16 + quad*4 + r)
    unsigned mbits = 0;
    {
        const int* mp = mask + b * 1024 + sbase + quad * 4;
#pragma unroll
        for (int j = 0; j < 8; j++) {
            int4 m4 = *(const int4*)(mp + j * 16);
            mbits |= (unsigned)(m4.x != 0) << (j * 4 + 0);
            mbits |= (unsigned)(m4.y != 0) << (j * 4 + 1);
            mbits |= (unsigned)(m4.z != 0) << (j * 4 + 2);
            mbits |= (unsigned)(m4.w != 0) << (j * 4 + 3);
        }
    }

    // per-lane bases
    const float* const bb = bias + (((size_t)(b * 16)) << 20) +
                            (((size_t)(t0 + lq)) << 10) + sbase + quad * 4;
    const __bf16* const qp0 = qTb + (((size_t)(b * 16) * 1024 + t0) << 5) +
                              lq * 32 + quad * 8;
    const __bf16* const kp0 = kTb + ((size_t)(b * 16) << 15);
    const __bf16* const vp0 = vTb + ((size_t)(b * 16) << 15);

    // prologue (FIFO: qa(0), K(0), bias(0) -> first QK's wait is clean)
    bf16x8 qa = *(const bf16x8*)qp0;
    bf16x8 kbA[8], kbB[8];
#pragma unroll
    for (int j = 0; j < 8; j++)
        kbA[j] = *(const bf16x8*)(kp0 + (size_t)(sbase + j * 16 + lq) * 32 + quad * 8);
    f32x4 cj[8];
#pragma unroll
    for (int j = 0; j < 8; j++) cj[j] = *(const f32x4*)(bb + j * 16);

    float avg_reg[32] = {};

    // body: consumes kbC/cj/qa (all issued one body earlier); refills
    // kbN <- K(h+1), cj <- bias(h+1), qa <- Q(h+1) as the youngest VMEM.
    auto body = [&](bf16x8 (&kbC)[8], bf16x8 (&kbN)[8], int hh) {
        float* const Op  = Op0  + (hh & 1) * 4224;
        float* const red = red0 + (hh & 1) * 128;
        const __bf16* vp = vp0 + ((size_t)hh << 15);

        // V for this head (younger than everything QK waits on)
        bf16x8 v0r[4], v1r[4];
#pragma unroll
        for (int ks = 0; ks < 4; ks++) {
            v0r[ks] = *(const bf16x8*)(vp + (size_t)lq * 1024 + sbase + ks * 32 + quad * 8);
            v1r[ks] = *(const bf16x8*)(vp + (size_t)(16 + lq) * 1024 + sbase + ks * 32 + quad * 8);
        }
        __builtin_amdgcn_sched_barrier(0);

        // QK: operands issued one full body ago; wait leaves V(h) in flight.
        f32x4 acc[8];
#pragma unroll
        for (int j = 0; j < 8; j++)
            acc[j] = __builtin_amdgcn_mfma_f32_16x16x32_bf16(kbC[j], qa, cj[j], 0, 0, 0);
        __builtin_amdgcn_sched_barrier(0);

        // prefetch next head (youngest VMEM; branchless wrap)
        {
            const int h1 = (hh + 1) & 15;
            qa = *(const bf16x8*)(qp0 + ((size_t)h1 << 15));
            const __bf16* kpn = kp0 + ((size_t)h1 << 15);
#pragma unroll
            for (int j = 0; j < 8; j++)
                kbN[j] = *(const bf16x8*)(kpn + (size_t)(sbase + j * 16 + lq) * 32 + quad * 8);
            const float* bn = bb + ((size_t)h1 << 20);
#pragma unroll
            for (int j = 0; j < 8; j++) cj[j] = *(const f32x4*)(bn + j * 16);
        }
        __builtin_amdgcn_sched_barrier(0);

        // exp (no max pass; scores bounded) + mask + row partial sum
        float sm = 0.f;
#pragma unroll
        for (int j = 0; j < 8; j++)
#pragma unroll
            for (int r = 0; r < 4; r++) {
                float p = __expf(acc[j][r]);
                p = ((mbits >> (j * 4 + r)) & 1u) ? 0.f : p;
                acc[j][r] = p;
                sm += p;
            }
        sm += __shfl_xor(sm, 16);
        sm += __shfl_xor(sm, 32);

        // unnormalized bf16 P into per-wave LDS region (same-wave use only)
#pragma unroll
        for (int j = 0; j < 8; j++) {
            bf16x4 pv;
            pv[0] = (__bf16)acc[j][0]; pv[1] = (__bf16)acc[j][1];
            pv[2] = (__bf16)acc[j][2]; pv[3] = (__bf16)acc[j][3];
            *(bf16x4*)&Pw[lq * 136 + j * 16 + quad * 4] = pv;
        }
        if (lane < 16) red[w * 16 + lane] = sm;

        // PV: P from LDS (lgkmcnt only), V from registers
        f32x4 o0 = {0.f, 0.f, 0.f, 0.f}, o1 = {0.f, 0.f, 0.f, 0.f};
#pragma unroll
        for (int ks = 0; ks < 4; ks++) {
            bf16x8 pa = *(const bf16x8*)&Pw[lq * 136 + ks * 32 + quad * 8];
            o0 = __builtin_amdgcn_mfma_f32_16x16x32_bf16(pa, v0r[ks], o0, 0, 0, 0);
            o1 = __builtin_amdgcn_mfma_f32_16x16x32_bf16(pa, v1r[ks], o1, 0, 0, 0);
        }
#pragma unroll
        for (int r = 0; r < 4; r++) {
            Op[w * 528 + (quad * 4 + r) * 33 + lq]      = o0[r];
            Op[w * 528 + (quad * 4 + r) * 33 + 16 + lq] = o1[r];
        }

        // raw barrier: drain LDS only; prefetches (VMEM) stay in flight.
        __builtin_amdgcn_sched_barrier(0);
        asm volatile("s_waitcnt lgkmcnt(0)" ::: "memory");
        __builtin_amdgcn_s_barrier();
        __builtin_amdgcn_sched_barrier(0);

        // cross-wave reduce: normalized O write
        {
            const int t = tid >> 5, d = tid & 31;
            float s = 0.f, o = 0.f;
#pragma unroll
            for (int w2 = 0; w2 < 8; w2++) s += red[w2 * 16 + t];
#pragma unroll
            for (int w2 = 0; w2 < 8; w2++) o += Op[w2 * 528 + t * 33 + d];
            attnb[((size_t)(t0 + t) * 4 + b) * 512 + hh * 32 + d] = (__bf16)(o / s);
        }

        // inv for this lane's rows (t = lq) + avg fold; acc dies here
        float s_all = 0.f;
#pragma unroll
        for (int w2 = 0; w2 < 8; w2++) s_all += red[w2 * 16 + lq];
        const float inv = 1.0f / s_all;
#pragma unroll
        for (int j = 0; j < 8; j++)
#pragma unroll
            for (int r = 0; r < 4; r++)
                avg_reg[j * 4 + r] += acc[j][r] * inv;
    };

    for (int hp = 0; hp < 8; hp++) {
        body(kbA, kbB, hp * 2);
        body(kbB, kbA, hp * 2 + 1);
    }

    // head-mean store: single fp32 write (all 16 heads accumulated here)
    float* ap = avgf + ((size_t)(b * 1024 + t0 + lq) << 10) + sbase + quad * 4;
#pragma unroll
    for (int j = 0; j < 8; j++) {
        f32x4 v = { avg_reg[j * 4 + 0] * 0.0625f, avg_reg[j * 4 + 1] * 0.0625f,
                    avg_reg[j * 4 + 2] * 0.0625f, avg_reg[j * 4 + 3] * 0.0625f };
        *(f32x4*)(ap + j * 16) = v;
    }
}

// ---------------------------------------------------------------------------
extern "C" void kernel_launch(void* const* d_in, const int* in_sizes, int n_in,
                              void* d_out, int out_size, void* d_ws, size_t ws_size,
                              hipStream_t stream)
{
    const float* query     = (const float*)d_in[0];
    const float* attn_bias = (const float*)d_in[1];
    const int*   mask      = (const int*)d_in[2];
    const float* q_w       = (const float*)d_in[3];
    const float* q_b       = (const float*)d_in[4];
    const float* k_w       = (const float*)d_in[5];
    const float* k_b       = (const float*)d_in[6];
    const float* v_w       = (const float*)d_in[7];
    const float* v_b       = (const float*)d_in[8];
    const float* out_w     = (const float*)d_in[9];
    const float* out_b     = (const float*)d_in[10];

    float* out     = (float*)d_out;                 // [1024,4,512]
    float* avg_out = out + (size_t)2097152;         // [4,1024,1024]

    char* wsb = (char*)d_ws;
    __bf16* Wqb   = (__bf16*)(wsb);                         // 512 KB
    __bf16* Wkb   = (__bf16*)(wsb + ((size_t)512 << 10));
    __bf16* Wvb   = (__bf16*)(wsb + ((size_t)1 << 20));
    __bf16* Wob   = (__bf16*)(wsb + ((size_t)1 << 20) + ((size_t)512 << 10));
    __bf16* qTb   = (__bf16*)(wsb + ((size_t)2  << 20));    // 4 MB [64][1024][32]
    __bf16* kTb   = (__bf16*)(wsb + ((size_t)6  << 20));    // 4 MB [64][1024][32]
    __bf16* vTb   = (__bf16*)(wsb + ((size_t)10 << 20));    // 4 MB [64][32][1024]
    __bf16* attnb = (__bf16*)(wsb + ((size_t)14 << 20));    // 4 MB [4096][512]

    cvt_w<<<dim3(128, 4), dim3(256), 0, stream>>>(
        q_w, k_w, v_w, out_w, Wqb, Wkb, Wvb, Wob);

    qkv_proj<<<dim3(64, 4), dim3(256), 0, stream>>>(
        query, Wqb, Wkb, Wvb, q_b, k_b, v_b, qTb, kTb, vTb);

    attn_mfma<<<dim3(64, 4), dim3(512), 0, stream>>>(
        qTb, kTb, vTb, attn_bias, mask, attnb, avg_out);

    out_proj<<<dim3(64, 4), dim3(256), 0, stream>>>(attnb, Wob, out_b, out);
}